// Round 2
// baseline (8165.915 us; speedup 1.0000x reference)
//
#include <hip/hip_runtime.h>

#define B_ 2048
#define S_ 128
#define D_ 1024
#define H_ 2048
#define E_ 8
#define NC 10
#define STEPS_ 5

constexpr int BM = 64, BN = 128, BK = 16;

// ---------------------------------------------------------------------------
// Pool: h[b] = masked mean over S of emb[ids[b,s]]; also init active list.
// ---------------------------------------------------------------------------
__global__ __launch_bounds__(256) void pool_kernel(
    const int* __restrict__ ids, const float* __restrict__ emb,
    float* __restrict__ h, int* __restrict__ al, int* __restrict__ n_act)
{
    const int b = blockIdx.x;
    const int t = threadIdx.x;
    __shared__ int sid[S_];
    __shared__ float scnt;
    if (t < S_) sid[t] = ids[b * S_ + t];
    __syncthreads();
    if (t == 0) {
        int c = 0;
        for (int j = 0; j < S_; j++) c += (sid[j] != 0) ? 1 : 0;
        scnt = (c > 0) ? (float)c : 1.0f;
    }
    const int d0 = t * 4;
    float ax = 0.f, ay = 0.f, az = 0.f, aw = 0.f;
    for (int j = 0; j < S_; j++) {
        const int id = sid[j];
        if (id != 0) {  // wave-uniform branch (sid[j] is broadcast)
            const float4 v = *(const float4*)(emb + (size_t)id * D_ + d0);
            ax += v.x; ay += v.y; az += v.z; aw += v.w;
        }
    }
    __syncthreads();
    const float c = scnt;
    float4 r; r.x = ax / c; r.y = ay / c; r.z = az / c; r.w = aw / c;
    *(float4*)(h + (size_t)b * D_ + d0) = r;
    if (t == 0) {
        al[b] = b;
        if (b == 0) *n_act = B_;
    }
}

// ---------------------------------------------------------------------------
// Generic gathered-row fp32 GEMM:
//   for i in [0, counts[z]):  C[rows[i]] = op( A[rows[i]] @ W_z + bias_z )
// 64x128 tile, 256 threads, 4x8 acc/thread, BK=16.
// Ping-pong LDS double buffer, ONE barrier per K-iter.
// B fragment = cols [4tx,4tx+4) and [64+4tx,64+4tx+4)  -> 2-way LDS alias (free).
// ---------------------------------------------------------------------------
__global__ __launch_bounds__(256) void gemm_gather(
    const float* __restrict__ A, int a_rs,
    const float* __restrict__ W, long long w_es, int N,
    const float* __restrict__ bias, int bias_es, int has_bias,
    float* __restrict__ C, int c_rs,
    const int* __restrict__ rows, int rows_es,
    const int* __restrict__ counts,
    int K, int do_relu)
{
    const int e = blockIdx.z;
    const int cnt = counts[e];
    const int m0 = blockIdx.x * BM;
    if (m0 >= cnt) return;
    const int n0 = blockIdx.y * BN;

    const float* We = W + (size_t)e * (size_t)w_es + n0;
    const int* rowse = rows + (size_t)e * rows_es;

    __shared__ float As[2][BK][BM + 4];
    __shared__ float Bs[2][BK][BN];

    const int tid = threadIdx.x;
    // A stage: 64 rows x 16 k / 256 thr = one float4 along k each
    const int l_ar = tid >> 2;
    const int l_ak = (tid & 3) << 2;
    const int arow_i = m0 + l_ar;
    const int arow = rowse[arow_i < cnt ? arow_i : (cnt - 1)];
    const float* Ap = A + (size_t)arow * a_rs + l_ak;
    // B stage: rows l_bk and l_bk+8, cols l_bn..l_bn+4
    const int l_bk = tid >> 5;
    const int l_bn = (tid & 31) << 2;
    const float* Bp = We + (size_t)l_bk * N + l_bn;

    const int tx = tid & 15;   // col group: 4tx and 64+4tx
    const int ty = tid >> 4;   // row group (x4)

    float acc[4][8];
#pragma unroll
    for (int i = 0; i < 4; i++)
#pragma unroll
        for (int j = 0; j < 8; j++) acc[i][j] = 0.f;

    // prologue: load k-block 0, stage to LDS[0]
    float4 av  = *(const float4*)(Ap);
    float4 bv0 = *(const float4*)(Bp);
    float4 bv1 = *(const float4*)(Bp + (size_t)8 * N);
    As[0][l_ak + 0][l_ar] = av.x;
    As[0][l_ak + 1][l_ar] = av.y;
    As[0][l_ak + 2][l_ar] = av.z;
    As[0][l_ak + 3][l_ar] = av.w;
    *(float4*)&Bs[0][l_bk][l_bn] = bv0;
    *(float4*)&Bs[0][l_bk + 8][l_bn] = bv1;
    __syncthreads();

    const int nk = K / BK;
    int buf = 0;
    for (int k0 = 0; k0 < nk; k0++) {
        const bool more = (k0 + 1) < nk;
        if (more) {
            const int koff = (k0 + 1) * BK;
            av  = *(const float4*)(Ap + koff);
            bv0 = *(const float4*)(Bp + (size_t)koff * N);
            bv1 = *(const float4*)(Bp + (size_t)(koff + 8) * N);
        }
        const float (* __restrict__ Asb)[BM + 4] = As[buf];
        const float (* __restrict__ Bsb)[BN] = Bs[buf];
#pragma unroll
        for (int k = 0; k < BK; k++) {
            const float4 a  = *(const float4*)&Asb[k][ty * 4];
            const float4 b0 = *(const float4*)&Bsb[k][tx * 4];
            const float4 b1 = *(const float4*)&Bsb[k][64 + tx * 4];
            const float ar[4] = {a.x, a.y, a.z, a.w};
            const float br[8] = {b0.x, b0.y, b0.z, b0.w, b1.x, b1.y, b1.z, b1.w};
#pragma unroll
            for (int i = 0; i < 4; i++)
#pragma unroll
                for (int j = 0; j < 8; j++)
                    acc[i][j] = fmaf(ar[i], br[j], acc[i][j]);
        }
        if (more) {
            const int nb = buf ^ 1;
            As[nb][l_ak + 0][l_ar] = av.x;
            As[nb][l_ak + 1][l_ar] = av.y;
            As[nb][l_ak + 2][l_ar] = av.z;
            As[nb][l_ak + 3][l_ar] = av.w;
            *(float4*)&Bs[nb][l_bk][l_bn] = bv0;
            *(float4*)&Bs[nb][l_bk + 8][l_bn] = bv1;
            __syncthreads();
            buf = nb;
        }
    }

    const float* be = has_bias ? (bias + (size_t)e * bias_es + n0) : nullptr;
    float bb[8];
    if (has_bias) {
#pragma unroll
        for (int j = 0; j < 4; j++) bb[j] = be[tx * 4 + j];
#pragma unroll
        for (int j = 0; j < 4; j++) bb[4 + j] = be[64 + tx * 4 + j];
    }
#pragma unroll
    for (int i = 0; i < 4; i++) {
        const int mi = m0 + ty * 4 + i;
        if (mi < cnt) {
            const int r = rowse[mi];
            float* Cr = C + (size_t)r * c_rs + n0;
            float v[8];
#pragma unroll
            for (int j = 0; j < 8; j++) {
                float x = acc[i][j];
                if (has_bias) x += bb[j];
                if (do_relu) x = fmaxf(x, 0.f);
                v[j] = x;
            }
            float4 v0 = {v[0], v[1], v[2], v[3]};
            float4 v1 = {v[4], v[5], v[6], v[7]};
            *(float4*)(Cr + tx * 4) = v0;
            *(float4*)(Cr + 64 + tx * 4) = v1;
        }
    }
}

// ---------------------------------------------------------------------------
// Router stage 2: logits = rhid @ rW2 + rb2 (per active sample), argmax,
// terminate (copy h->final) or bucket into per-expert lists + next active list.
// One wave per sample.
// ---------------------------------------------------------------------------
__global__ __launch_bounds__(256) void router2_kernel(
    const float* __restrict__ rhid, const float* __restrict__ rW2,
    const float* __restrict__ rb2, const float* __restrict__ h,
    float* __restrict__ final_, const int* __restrict__ al,
    const int* __restrict__ n_act, int* __restrict__ counts,
    int* __restrict__ bucket, int* __restrict__ al_next,
    int* __restrict__ n_next, int* __restrict__ act_sel)
{
    const int n = *n_act;
    const int wid = threadIdx.x >> 6;
    const int lane = threadIdx.x & 63;
    const int i = blockIdx.x * 4 + wid;
    if (i >= n) return;
    const int s = al[i];
    const float* x = rhid + (size_t)s * D_;
    float acc[E_ + 1];
#pragma unroll
    for (int c = 0; c <= E_; c++) acc[c] = 0.f;
    for (int j = 0; j < D_ / 64; j++) {
        const int d = j * 64 + lane;
        const float xv = x[d];
        const float* wr = rW2 + (size_t)d * (E_ + 1);
#pragma unroll
        for (int c = 0; c <= E_; c++) acc[c] = fmaf(xv, wr[c], acc[c]);
    }
#pragma unroll
    for (int c = 0; c <= E_; c++) {
        float v = acc[c];
        for (int off = 32; off > 0; off >>= 1) v += __shfl_down(v, off, 64);
        acc[c] = v;
    }
    int best = 0;
    if (lane == 0) {
        float bv = acc[0] + rb2[0];
#pragma unroll
        for (int c = 1; c <= E_; c++) {
            const float v = acc[c] + rb2[c];
            if (v > bv) { bv = v; best = c; }   // strict '>' = first-max (np argmax)
        }
    }
    best = __shfl(best, 0, 64);
    if (best == E_) {
        const float* hs = h + (size_t)s * D_;
        float* fs = final_ + (size_t)s * D_;
        for (int d = lane * 4; d < D_; d += 64 * 4)
            *(float4*)(fs + d) = *(const float4*)(hs + d);
    } else if (lane == 0) {
        const int p = atomicAdd(&counts[best], 1);
        bucket[best * B_ + p] = s;
        const int q = atomicAdd(n_next, 1);
        al_next[q] = s;
        act_sel[s] = best;
    }
}

// ---------------------------------------------------------------------------
// LN + residual: h[s] += LN(Y[s] + b2_e) * g_e + beta_e  for routed samples.
// One block per sample (ghost blocks exit).
// ---------------------------------------------------------------------------
__global__ __launch_bounds__(256) void ln_update_kernel(
    float* __restrict__ h, const float* __restrict__ Y,
    const float* __restrict__ eb2, const float* __restrict__ eg,
    const float* __restrict__ ebeta, const int* __restrict__ al,
    const int* __restrict__ n_ptr, const int* __restrict__ act_sel)
{
    const int n = *n_ptr;
    const int i = blockIdx.x;
    if (i >= n) return;
    const int s = al[i];
    const int e = act_sel[s];
    const int t = threadIdx.x;
    const int lane = t & 63, wid = t >> 6;
    const int d0 = t * 4;

    const float4 yv = *(const float4*)(Y + (size_t)s * D_ + d0);
    const float4 bv = *(const float4*)(eb2 + (size_t)e * D_ + d0);
    float y0 = yv.x + bv.x, y1 = yv.y + bv.y, y2 = yv.z + bv.z, y3 = yv.w + bv.w;

    __shared__ float wsum[4];
    __shared__ float stats[2];

    float ssum = y0 + y1 + y2 + y3;
    for (int off = 32; off > 0; off >>= 1) ssum += __shfl_down(ssum, off, 64);
    if (lane == 0) wsum[wid] = ssum;
    __syncthreads();
    if (t == 0) stats[0] = (wsum[0] + wsum[1] + wsum[2] + wsum[3]) * (1.f / D_);
    __syncthreads();
    const float m = stats[0];
    const float e0 = y0 - m, e1 = y1 - m, e2 = y2 - m, e3 = y3 - m;
    float sq = e0 * e0 + e1 * e1 + e2 * e2 + e3 * e3;
    for (int off = 32; off > 0; off >>= 1) sq += __shfl_down(sq, off, 64);
    if (lane == 0) wsum[wid] = sq;
    __syncthreads();
    if (t == 0) {
        const float var = (wsum[0] + wsum[1] + wsum[2] + wsum[3]) * (1.f / D_);
        stats[1] = 1.0f / sqrtf(var + 1e-5f);
    }
    __syncthreads();
    const float rs = stats[1];

    const float4 gv = *(const float4*)(eg + (size_t)e * D_ + d0);
    const float4 btv = *(const float4*)(ebeta + (size_t)e * D_ + d0);
    float* hp = h + (size_t)s * D_ + d0;
    float4 hv = *(const float4*)hp;
    hv.x += e0 * rs * gv.x + btv.x;
    hv.y += e1 * rs * gv.y + btv.y;
    hv.z += e2 * rs * gv.z + btv.z;
    hv.w += e3 * rs * gv.w + btv.w;
    *(float4*)hp = hv;
}

__global__ void reset_kernel(int* __restrict__ counts, int* __restrict__ n_next)
{
    const int t = threadIdx.x;
    if (t < E_) counts[t] = 0;
    if (t == E_) *n_next = 0;
}

__global__ __launch_bounds__(256) void finalize_kernel(
    const int* __restrict__ al, const int* __restrict__ n_ptr,
    const float* __restrict__ h, float* __restrict__ final_)
{
    const int n = *n_ptr;
    const int i = blockIdx.x;
    if (i >= n) return;
    const int s = al[i];
    const int d0 = threadIdx.x * 4;
    *(float4*)(final_ + (size_t)s * D_ + d0) =
        *(const float4*)(h + (size_t)s * D_ + d0);
}

// out[s, 0..9] = final[s] @ oW + ob
__global__ __launch_bounds__(256) void out_head_kernel(
    const float* __restrict__ final_, const float* __restrict__ oW,
    const float* __restrict__ ob, float* __restrict__ out)
{
    const int s = blockIdx.x;
    const int t = threadIdx.x;
    const int lane = t & 63, wid = t >> 6;
    float p[NC];
#pragma unroll
    for (int c = 0; c < NC; c++) p[c] = 0.f;
    for (int d = t; d < D_; d += 256) {
        const float x = final_[(size_t)s * D_ + d];
        const float* wr = oW + (size_t)d * NC;
#pragma unroll
        for (int c = 0; c < NC; c++) p[c] = fmaf(x, wr[c], p[c]);
    }
#pragma unroll
    for (int c = 0; c < NC; c++) {
        float v = p[c];
        for (int off = 32; off > 0; off >>= 1) v += __shfl_down(v, off, 64);
        p[c] = v;
    }
    __shared__ float red[4][NC];
    if (lane == 0) {
#pragma unroll
        for (int c = 0; c < NC; c++) red[wid][c] = p[c];
    }
    __syncthreads();
    if (t < NC)
        out[(size_t)s * NC + t] =
            red[0][t] + red[1][t] + red[2][t] + red[3][t] + ob[t];
}

// ---------------------------------------------------------------------------
extern "C" void kernel_launch(void* const* d_in, const int* in_sizes, int n_in,
                              void* d_out, int out_size, void* d_ws, size_t ws_size,
                              hipStream_t stream)
{
    const int*   ids   = (const int*)d_in[0];
    const float* emb   = (const float*)d_in[1];
    const float* rW1   = (const float*)d_in[2];
    const float* rb1   = (const float*)d_in[3];
    const float* rW2   = (const float*)d_in[4];
    const float* rb2   = (const float*)d_in[5];
    const float* eW1   = (const float*)d_in[6];
    const float* eb1   = (const float*)d_in[7];
    const float* eW2   = (const float*)d_in[8];
    const float* eb2   = (const float*)d_in[9];
    const float* eg    = (const float*)d_in[10];
    const float* ebeta = (const float*)d_in[11];
    const float* oW    = (const float*)d_in[12];
    const float* ob    = (const float*)d_in[13];
    float* out = (float*)d_out;

    // workspace layout (fp32 buffers first, then ints)
    float* h     = (float*)d_ws;                 // B*D
    float* fin   = h + (size_t)B_ * D_;          // B*D
    float* rhidY = fin + (size_t)B_ * D_;        // B*D (router hidden, reused as Y)
    float* Z     = rhidY + (size_t)B_ * D_;      // B*H
    int* alA     = (int*)(Z + (size_t)B_ * H_);  // B
    int* alB     = alA + B_;                     // B
    int* bucket  = alB + B_;                     // E*B
    int* counts  = bucket + E_ * B_;             // E
    int* nA      = counts + E_;                  // 1
    int* nB      = nA + 1;                       // 1
    int* act_sel = nB + 1;                       // B

    pool_kernel<<<B_, 256, 0, stream>>>(ids, emb, h, alA, nA);

    int* al_in = alA; int* n_in_p = nA;
    int* al_out = alB; int* n_out_p = nB;

    for (int step = 0; step < STEPS_; step++) {
        reset_kernel<<<1, 64, 0, stream>>>(counts, n_out_p);

        // router hidden: rhid = relu(h @ rW1 + rb1), gathered over active list
        gemm_gather<<<dim3(B_ / BM, D_ / BN, 1), 256, 0, stream>>>(
            h, D_, rW1, 0, D_, rb1, 0, 1, rhidY, D_, al_in, 0, n_in_p, D_, 1);

        router2_kernel<<<B_ / 4, 256, 0, stream>>>(
            rhidY, rW2, rb2, h, fin, al_in, n_in_p,
            counts, bucket, al_out, n_out_p, act_sel);

        // expert layer 1: Z = relu(h @ eW1_e + eb1_e) for bucketed samples
        gemm_gather<<<dim3(B_ / BM, H_ / BN, E_), 256, 0, stream>>>(
            h, D_, eW1, (long long)D_ * H_, H_, eb1, H_, 1,
            Z, H_, bucket, B_, counts, D_, 1);

        // expert layer 2: Y = Z @ eW2_e (bias folded into LN kernel)
        gemm_gather<<<dim3(B_ / BM, D_ / BN, E_), 256, 0, stream>>>(
            Z, H_, eW2, (long long)H_ * D_, D_, nullptr, 0, 0,
            rhidY, D_, bucket, B_, counts, H_, 0);

        ln_update_kernel<<<B_, 256, 0, stream>>>(
            h, rhidY, eb2, eg, ebeta, al_out, n_out_p, act_sel);

        // swap active lists
        int* ta = al_in; al_in = al_out; al_out = ta;
        int* tn = n_in_p; n_in_p = n_out_p; n_out_p = tn;
    }

    finalize_kernel<<<B_, 256, 0, stream>>>(al_in, n_in_p, h, fin);
    out_head_kernel<<<B_, 256, 0, stream>>>(fin, oW, ob, out);
}

// Round 3
// 8069.231 us; speedup vs baseline: 1.0120x; 1.0120x over previous
//
#include <hip/hip_runtime.h>

#define B_ 2048
#define S_ 128
#define D_ 1024
#define H_ 2048
#define E_ 8
#define NC 10
#define STEPS_ 5

constexpr int BM = 64, BN = 64, BK = 16;

// ---------------------------------------------------------------------------
// Pool: h[b] = masked mean over S of emb[ids[b,s]]; also init active list.
// ---------------------------------------------------------------------------
__global__ __launch_bounds__(256) void pool_kernel(
    const int* __restrict__ ids, const float* __restrict__ emb,
    float* __restrict__ h, int* __restrict__ al, int* __restrict__ n_act)
{
    const int b = blockIdx.x;
    const int t = threadIdx.x;
    __shared__ int sid[S_];
    __shared__ float scnt;
    if (t < S_) sid[t] = ids[b * S_ + t];
    __syncthreads();
    if (t == 0) {
        int c = 0;
        for (int j = 0; j < S_; j++) c += (sid[j] != 0) ? 1 : 0;
        scnt = (c > 0) ? (float)c : 1.0f;
    }
    const int d0 = t * 4;
    float ax = 0.f, ay = 0.f, az = 0.f, aw = 0.f;
    for (int j = 0; j < S_; j++) {
        const int id = sid[j];
        if (id != 0) {  // wave-uniform branch (sid[j] is broadcast)
            const float4 v = *(const float4*)(emb + (size_t)id * D_ + d0);
            ax += v.x; ay += v.y; az += v.z; aw += v.w;
        }
    }
    __syncthreads();
    const float c = scnt;
    float4 r; r.x = ax / c; r.y = ay / c; r.z = az / c; r.w = aw / c;
    *(float4*)(h + (size_t)b * D_ + d0) = r;
    if (t == 0) {
        al[b] = b;
        if (b == 0) *n_act = B_;
    }
}

__global__ __launch_bounds__(256) void zero_kernel(float* __restrict__ p, int n4)
{
    const int i = blockIdx.x * 256 + threadIdx.x;
    if (i < n4) {
        float4 z = {0.f, 0.f, 0.f, 0.f};
        ((float4*)p)[i] = z;
    }
}

// ---------------------------------------------------------------------------
// Gathered-row fp32 GEMM with split-K atomic accumulation:
//   C[rows[i]] += op_A(A[rows[i]]) @ W_e    over k-chunk kc of split_k
// op_A(x) = relu(x + a_bias_e) when a_bias != null (expert-L2 consumes Z).
// Tile 64x64, 256 threads, 4x4 acc/thread, BK=16, two-barrier + reg prefetch.
// Grid: (m_tiles, N/64, E*split_k). C must be pre-zeroed.
// ---------------------------------------------------------------------------
__global__ __launch_bounds__(256, 6) void gemm_gather_acc(
    const float* __restrict__ A, int a_rs,
    const float* __restrict__ a_bias,          // [E][K] or null
    const float* __restrict__ W, long long w_es, int N,
    float* __restrict__ C, int c_rs,
    const int* __restrict__ rows, int rows_es,
    const int* __restrict__ counts,
    int K, int split_k)
{
    const int z = blockIdx.z;
    const int e = z / split_k;
    const int kc = z - e * split_k;
    const int cnt = counts[e];
    const int m0 = blockIdx.x * BM;
    if (m0 >= cnt) return;
    const int n0 = blockIdx.y * BN;
    const int Kc = K / split_k;
    const int kb0 = kc * Kc;

    const float* We = W + (size_t)e * (size_t)w_es + (size_t)kb0 * N + n0;
    const int* rowse = rows + (size_t)e * rows_es;
    const float* abe = a_bias ? (a_bias + (size_t)e * K + kb0) : nullptr;

    __shared__ float As[BK][BM + 4];   // transposed A tile, stride 68
    __shared__ float Bs[BK][BN];

    const int tid = threadIdx.x;
    // A stage: 64 rows x 16 k / 256 thr = one float4 along k
    const int l_ar = tid >> 2;
    const int l_ak = (tid & 3) << 2;
    const int arow_i = m0 + l_ar;
    const int arow = rowse[arow_i < cnt ? arow_i : (cnt - 1)];
    const float* Ap = A + (size_t)arow * a_rs + kb0 + l_ak;
    // B stage: 16 k x 64 n / 256 thr = one float4 along n
    const int l_bk = tid >> 4;
    const int l_bn = (tid & 15) << 2;
    const float* Bp = We + (size_t)l_bk * N + l_bn;

    const int tx = tid & 15;   // 4 cols at 4*tx
    const int ty = tid >> 4;   // 4 rows at 4*ty

    float acc[4][4];
#pragma unroll
    for (int i = 0; i < 4; i++)
#pragma unroll
        for (int j = 0; j < 4; j++) acc[i][j] = 0.f;

    float4 av = *(const float4*)(Ap);
    float4 bv = *(const float4*)(Bp);
    if (abe) {
        const float4 ab = *(const float4*)(abe + l_ak);
        av.x = fmaxf(av.x + ab.x, 0.f);
        av.y = fmaxf(av.y + ab.y, 0.f);
        av.z = fmaxf(av.z + ab.z, 0.f);
        av.w = fmaxf(av.w + ab.w, 0.f);
    }

    const int nk = Kc / BK;
    for (int k0 = 0; k0 < nk; k0++) {
        __syncthreads();
        As[l_ak + 0][l_ar] = av.x;
        As[l_ak + 1][l_ar] = av.y;
        As[l_ak + 2][l_ar] = av.z;
        As[l_ak + 3][l_ar] = av.w;
        *(float4*)&Bs[l_bk][l_bn] = bv;
        __syncthreads();
        if (k0 + 1 < nk) {
            const int koff = (k0 + 1) * BK;
            av = *(const float4*)(Ap + koff);
            bv = *(const float4*)(Bp + (size_t)koff * N);
            if (abe) {
                const float4 ab = *(const float4*)(abe + l_ak + koff);
                av.x = fmaxf(av.x + ab.x, 0.f);
                av.y = fmaxf(av.y + ab.y, 0.f);
                av.z = fmaxf(av.z + ab.z, 0.f);
                av.w = fmaxf(av.w + ab.w, 0.f);
            }
        }
#pragma unroll
        for (int k = 0; k < BK; k++) {
            const float4 a = *(const float4*)&As[k][ty * 4];
            const float4 b = *(const float4*)&Bs[k][tx * 4];
            const float ar[4] = {a.x, a.y, a.z, a.w};
            const float br[4] = {b.x, b.y, b.z, b.w};
#pragma unroll
            for (int i = 0; i < 4; i++)
#pragma unroll
                for (int j = 0; j < 4; j++)
                    acc[i][j] = fmaf(ar[i], br[j], acc[i][j]);
        }
    }

#pragma unroll
    for (int i = 0; i < 4; i++) {
        const int mi = m0 + ty * 4 + i;
        if (mi < cnt) {
            const int r = rowse[mi];
            float* Cr = C + (size_t)r * c_rs + n0 + tx * 4;
            atomicAdd(Cr + 0, acc[i][0]);
            atomicAdd(Cr + 1, acc[i][1]);
            atomicAdd(Cr + 2, acc[i][2]);
            atomicAdd(Cr + 3, acc[i][3]);
        }
    }
}

// ---------------------------------------------------------------------------
// Router stage 2: logits = relu(rhid + rb1) @ rW2 + rb2, argmax,
// terminate (copy h->final) or bucket into per-expert lists + next active list.
// One wave per sample. (rb1/relu folded here; rhid is the raw split-K sum.)
// ---------------------------------------------------------------------------
__global__ __launch_bounds__(256) void router2_kernel(
    const float* __restrict__ rhid, const float* __restrict__ rb1,
    const float* __restrict__ rW2, const float* __restrict__ rb2,
    const float* __restrict__ h,
    float* __restrict__ final_, const int* __restrict__ al,
    const int* __restrict__ n_act, int* __restrict__ counts,
    int* __restrict__ bucket, int* __restrict__ al_next,
    int* __restrict__ n_next, int* __restrict__ act_sel)
{
    const int n = *n_act;
    const int wid = threadIdx.x >> 6;
    const int lane = threadIdx.x & 63;
    const int i = blockIdx.x * 4 + wid;
    if (i >= n) return;
    const int s = al[i];
    const float* x = rhid + (size_t)s * D_;
    float acc[E_ + 1];
#pragma unroll
    for (int c = 0; c <= E_; c++) acc[c] = 0.f;
    for (int j = 0; j < D_ / 64; j++) {
        const int d = j * 64 + lane;
        const float xv = fmaxf(x[d] + rb1[d], 0.f);
        const float* wr = rW2 + (size_t)d * (E_ + 1);
#pragma unroll
        for (int c = 0; c <= E_; c++) acc[c] = fmaf(xv, wr[c], acc[c]);
    }
#pragma unroll
    for (int c = 0; c <= E_; c++) {
        float v = acc[c];
        for (int off = 32; off > 0; off >>= 1) v += __shfl_down(v, off, 64);
        acc[c] = v;
    }
    int best = 0;
    if (lane == 0) {
        float bv = acc[0] + rb2[0];
#pragma unroll
        for (int c = 1; c <= E_; c++) {
            const float v = acc[c] + rb2[c];
            if (v > bv) { bv = v; best = c; }   // strict '>' = first-max (np argmax)
        }
    }
    best = __shfl(best, 0, 64);
    if (best == E_) {
        const float* hs = h + (size_t)s * D_;
        float* fs = final_ + (size_t)s * D_;
        for (int d = lane * 4; d < D_; d += 64 * 4)
            *(float4*)(fs + d) = *(const float4*)(hs + d);
    } else if (lane == 0) {
        const int p = atomicAdd(&counts[best], 1);
        bucket[best * B_ + p] = s;
        const int q = atomicAdd(n_next, 1);
        al_next[q] = s;
        act_sel[s] = best;
    }
}

// ---------------------------------------------------------------------------
// LN + residual: h[s] += LN(Y[s] + b2_e) * g_e + beta_e  for routed samples.
// ---------------------------------------------------------------------------
__global__ __launch_bounds__(256) void ln_update_kernel(
    float* __restrict__ h, const float* __restrict__ Y,
    const float* __restrict__ eb2, const float* __restrict__ eg,
    const float* __restrict__ ebeta, const int* __restrict__ al,
    const int* __restrict__ n_ptr, const int* __restrict__ act_sel)
{
    const int n = *n_ptr;
    const int i = blockIdx.x;
    if (i >= n) return;
    const int s = al[i];
    const int e = act_sel[s];
    const int t = threadIdx.x;
    const int lane = t & 63, wid = t >> 6;
    const int d0 = t * 4;

    const float4 yv = *(const float4*)(Y + (size_t)s * D_ + d0);
    const float4 bv = *(const float4*)(eb2 + (size_t)e * D_ + d0);
    float y0 = yv.x + bv.x, y1 = yv.y + bv.y, y2 = yv.z + bv.z, y3 = yv.w + bv.w;

    __shared__ float wsum[4];
    __shared__ float stats[2];

    float ssum = y0 + y1 + y2 + y3;
    for (int off = 32; off > 0; off >>= 1) ssum += __shfl_down(ssum, off, 64);
    if (lane == 0) wsum[wid] = ssum;
    __syncthreads();
    if (t == 0) stats[0] = (wsum[0] + wsum[1] + wsum[2] + wsum[3]) * (1.f / D_);
    __syncthreads();
    const float m = stats[0];
    const float e0 = y0 - m, e1 = y1 - m, e2 = y2 - m, e3 = y3 - m;
    float sq = e0 * e0 + e1 * e1 + e2 * e2 + e3 * e3;
    for (int off = 32; off > 0; off >>= 1) sq += __shfl_down(sq, off, 64);
    if (lane == 0) wsum[wid] = sq;
    __syncthreads();
    if (t == 0) {
        const float var = (wsum[0] + wsum[1] + wsum[2] + wsum[3]) * (1.f / D_);
        stats[1] = 1.0f / sqrtf(var + 1e-5f);
    }
    __syncthreads();
    const float rs = stats[1];

    const float4 gv = *(const float4*)(eg + (size_t)e * D_ + d0);
    const float4 btv = *(const float4*)(ebeta + (size_t)e * D_ + d0);
    float* hp = h + (size_t)s * D_ + d0;
    float4 hv = *(const float4*)hp;
    hv.x += e0 * rs * gv.x + btv.x;
    hv.y += e1 * rs * gv.y + btv.y;
    hv.z += e2 * rs * gv.z + btv.z;
    hv.w += e3 * rs * gv.w + btv.w;
    *(float4*)hp = hv;
}

__global__ void reset_kernel(int* __restrict__ counts, int* __restrict__ n_next)
{
    const int t = threadIdx.x;
    if (t < E_) counts[t] = 0;
    if (t == E_) *n_next = 0;
}

__global__ __launch_bounds__(256) void finalize_kernel(
    const int* __restrict__ al, const int* __restrict__ n_ptr,
    const float* __restrict__ h, float* __restrict__ final_)
{
    const int n = *n_ptr;
    const int i = blockIdx.x;
    if (i >= n) return;
    const int s = al[i];
    const int d0 = threadIdx.x * 4;
    *(float4*)(final_ + (size_t)s * D_ + d0) =
        *(const float4*)(h + (size_t)s * D_ + d0);
}

// out[s, 0..9] = final[s] @ oW + ob
__global__ __launch_bounds__(256) void out_head_kernel(
    const float* __restrict__ final_, const float* __restrict__ oW,
    const float* __restrict__ ob, float* __restrict__ out)
{
    const int s = blockIdx.x;
    const int t = threadIdx.x;
    const int lane = t & 63, wid = t >> 6;
    float p[NC];
#pragma unroll
    for (int c = 0; c < NC; c++) p[c] = 0.f;
    for (int d = t; d < D_; d += 256) {
        const float x = final_[(size_t)s * D_ + d];
        const float* wr = oW + (size_t)d * NC;
#pragma unroll
        for (int c = 0; c < NC; c++) p[c] = fmaf(x, wr[c], p[c]);
    }
#pragma unroll
    for (int c = 0; c < NC; c++) {
        float v = p[c];
        for (int off = 32; off > 0; off >>= 1) v += __shfl_down(v, off, 64);
        p[c] = v;
    }
    __shared__ float red[4][NC];
    if (lane == 0) {
#pragma unroll
        for (int c = 0; c < NC; c++) red[wid][c] = p[c];
    }
    __syncthreads();
    if (t < NC)
        out[(size_t)s * NC + t] =
            red[0][t] + red[1][t] + red[2][t] + red[3][t] + ob[t];
}

// ---------------------------------------------------------------------------
extern "C" void kernel_launch(void* const* d_in, const int* in_sizes, int n_in,
                              void* d_out, int out_size, void* d_ws, size_t ws_size,
                              hipStream_t stream)
{
    const int*   ids   = (const int*)d_in[0];
    const float* emb   = (const float*)d_in[1];
    const float* rW1   = (const float*)d_in[2];
    const float* rb1   = (const float*)d_in[3];
    const float* rW2   = (const float*)d_in[4];
    const float* rb2   = (const float*)d_in[5];
    const float* eW1   = (const float*)d_in[6];
    const float* eb1   = (const float*)d_in[7];
    const float* eW2   = (const float*)d_in[8];
    const float* eb2   = (const float*)d_in[9];
    const float* eg    = (const float*)d_in[10];
    const float* ebeta = (const float*)d_in[11];
    const float* oW    = (const float*)d_in[12];
    const float* ob    = (const float*)d_in[13];
    float* out = (float*)d_out;

    // workspace layout: h, fin, rhidY (router hidden / expert-Y), Z, ints
    float* h     = (float*)d_ws;                 // B*D
    float* fin   = h + (size_t)B_ * D_;          // B*D
    float* rhidY = fin + (size_t)B_ * D_;        // B*D
    float* Z     = rhidY + (size_t)B_ * D_;      // B*H  (contiguous after rhidY)
    int* alA     = (int*)(Z + (size_t)B_ * H_);  // B
    int* alB     = alA + B_;                     // B
    int* bucket  = alB + B_;                     // E*B
    int* counts  = bucket + E_ * B_;             // E
    int* nA      = counts + E_;                  // 1
    int* nB      = nA + 1;                       // 1
    int* act_sel = nB + 1;                       // B

    pool_kernel<<<B_, 256, 0, stream>>>(ids, emb, h, alA, nA);

    int* al_in = alA; int* n_in_p = nA;
    int* al_out = alB; int* n_out_p = nB;

    const int n4_rhid_Z = (B_ * D_ + B_ * H_) / 4;   // rhidY + Z contiguous
    const int n4_rhid   = (B_ * D_) / 4;

    for (int step = 0; step < STEPS_; step++) {
        reset_kernel<<<1, 64, 0, stream>>>(counts, n_out_p);
        zero_kernel<<<(n4_rhid_Z + 255) / 256, 256, 0, stream>>>(rhidY, n4_rhid_Z);

        // router hidden (raw): rhid += h @ rW1   (split-K 2; rb1+relu in router2)
        gemm_gather_acc<<<dim3(B_ / BM, D_ / BN, 2), 256, 0, stream>>>(
            h, D_, nullptr, rW1, 0, D_, rhidY, D_, al_in, 0, n_in_p, D_, 2);

        router2_kernel<<<B_ / 4, 256, 0, stream>>>(
            rhidY, rb1, rW2, rb2, h, fin, al_in, n_in_p,
            counts, bucket, al_out, n_out_p, act_sel);

        // expert L1 (raw): Z += h @ eW1_e   (split-K 2; eb1+relu applied by L2's A-load)
        gemm_gather_acc<<<dim3(B_ / BM, H_ / BN, E_ * 2), 256, 0, stream>>>(
            h, D_, nullptr, eW1, (long long)D_ * H_, H_,
            Z, H_, bucket, B_, counts, D_, 2);

        // re-zero Y region (router2 has consumed rhid by stream order)
        zero_kernel<<<(n4_rhid + 255) / 256, 256, 0, stream>>>(rhidY, n4_rhid);

        // expert L2: Y += relu(Z + eb1_e) @ eW2_e   (split-K 4; eb2 in LN kernel)
        gemm_gather_acc<<<dim3(B_ / BM, D_ / BN, E_ * 4), 256, 0, stream>>>(
            Z, H_, eb1, eW2, (long long)H_ * D_, D_,
            rhidY, D_, bucket, B_, counts, H_, 4);

        ln_update_kernel<<<B_, 256, 0, stream>>>(
            h, rhidY, eb2, eg, ebeta, al_out, n_out_p, act_sel);

        // swap active lists
        int* ta = al_in; al_in = al_out; al_out = ta;
        int* tn = n_in_p; n_in_p = n_out_p; n_out_p = tn;
    }

    finalize_kernel<<<B_, 256, 0, stream>>>(al_in, n_in_p, h, fin);
    out_head_kernel<<<B_, 256, 0, stream>>>(fin, oW, ob, out);
}

// Round 4
// 2565.707 us; speedup vs baseline: 3.1827x; 3.1450x over previous
//
#include <hip/hip_runtime.h>

#define B_ 2048
#define S_ 128
#define D_ 1024
#define H_ 2048
#define E_ 8
#define NC 10
#define STEPS_ 5

typedef __bf16 bf16_t;
typedef __bf16 bf16x8 __attribute__((ext_vector_type(8)));
typedef __bf16 bf16x4 __attribute__((ext_vector_type(4)));
typedef float f32x4 __attribute__((ext_vector_type(4)));

// ---------------------------------------------------------------------------
// Pool: h[b] = masked mean over S of emb[ids[b,s]]; emits fp32 h + bf16 hi/lo
// planes; inits active list.
// ---------------------------------------------------------------------------
__global__ __launch_bounds__(256) void pool_kernel(
    const int* __restrict__ ids, const float* __restrict__ emb,
    float* __restrict__ h, bf16_t* __restrict__ hhi, bf16_t* __restrict__ hlo,
    int* __restrict__ al, int* __restrict__ n_act)
{
    const int b = blockIdx.x;
    const int t = threadIdx.x;
    __shared__ int sid[S_];
    __shared__ float scnt;
    if (t < S_) sid[t] = ids[b * S_ + t];
    __syncthreads();
    if (t == 0) {
        int c = 0;
        for (int j = 0; j < S_; j++) c += (sid[j] != 0) ? 1 : 0;
        scnt = (c > 0) ? (float)c : 1.0f;
    }
    const int d0 = t * 4;
    float ax = 0.f, ay = 0.f, az = 0.f, aw = 0.f;
    for (int j = 0; j < S_; j++) {
        const int id = sid[j];
        if (id != 0) {
            const float4 v = *(const float4*)(emb + (size_t)id * D_ + d0);
            ax += v.x; ay += v.y; az += v.z; aw += v.w;
        }
    }
    __syncthreads();
    const float c = scnt;
    float r[4] = {ax / c, ay / c, az / c, aw / c};
    *(float4*)(h + (size_t)b * D_ + d0) = *(float4*)r;
    bf16x4 hv, lv;
#pragma unroll
    for (int q = 0; q < 4; q++) {
        bf16_t hb = (bf16_t)r[q];
        hv[q] = hb;
        lv[q] = (bf16_t)(r[q] - (float)hb);
    }
    *(bf16x4*)(hhi + (size_t)b * D_ + d0) = hv;
    *(bf16x4*)(hlo + (size_t)b * D_ + d0) = lv;
    if (t == 0) {
        al[b] = b;
        if (b == 0) *n_act = B_;
    }
}

// ---------------------------------------------------------------------------
// Weight convert+transpose: W[e][K][N] fp32 -> hi/lo bf16 planes [e][N][K].
// 32x32 tiles through LDS; grid (K/32, N/32, E).
// ---------------------------------------------------------------------------
__global__ __launch_bounds__(256) void conv_w_kernel(
    const float* __restrict__ W, bf16_t* __restrict__ hi, bf16_t* __restrict__ lo,
    int K, int N)
{
    const int e = blockIdx.z;
    const int k0 = blockIdx.x * 32, n0 = blockIdx.y * 32;
    const float* We = W + (size_t)e * K * N;
    bf16_t* he = hi + (size_t)e * N * K;
    bf16_t* le = lo + (size_t)e * N * K;
    __shared__ float t[32][33];
    const int tid = threadIdx.x;
    const int r = tid >> 3, c4 = (tid & 7) * 4;
    *(float4*)&t[r][c4] = *(const float4*)(We + (size_t)(k0 + r) * N + n0 + c4);
    __syncthreads();
    const int n = r, k4 = c4;
    bf16x4 hv, lv;
#pragma unroll
    for (int q = 0; q < 4; q++) {
        const float x = t[k4 + q][n];
        bf16_t hb = (bf16_t)x;
        hv[q] = hb;
        lv[q] = (bf16_t)(x - (float)hb);
    }
    *(bf16x4*)(he + (size_t)(n0 + n) * K + k0 + k4) = hv;
    *(bf16x4*)(le + (size_t)(n0 + n) * K + k0 + k4) = lv;
}

// ---------------------------------------------------------------------------
// Split-bf16 MFMA gathered GEMM.  C[rows[i]] = sum_k A[rows[i]][k] * W_e[k][n]
// A planes: [*][K] bf16 (k-contig). W planes: [e][N][K] bf16 (k-contig).
// Block 128x128, 4 waves x (64x64), BK=32 (one mfma-K per round).
// XOR-swizzled LDS chunks (16B), single barrier/round, depth-1 prefetch.
// mode 0: store fp32 partial to C + kc*c_es  (split-K, no bias)
// mode 2: x = relu(acc + bias[e][col]); split-store to Chi/Clo bf16 planes
// Grid: (ceil(maxM/128), N/128, E*split_k); ghost blocks exit on counts[e].
// ---------------------------------------------------------------------------
__global__ __launch_bounds__(256, 2) void gemm_mfma(
    const bf16_t* __restrict__ Ahi, const bf16_t* __restrict__ Alo, int a_rs,
    const bf16_t* __restrict__ Whi, const bf16_t* __restrict__ Wlo, long long w_es,
    int N, int K,
    const float* __restrict__ bias, int bias_es,
    float* __restrict__ C, long long c_es, int c_rs,
    bf16_t* __restrict__ Chi, bf16_t* __restrict__ Clo, int cp_rs,
    const int* __restrict__ rows, int rows_es,
    const int* __restrict__ counts,
    int split_k, int mode)
{
    const int z = blockIdx.z;
    const int e = z / split_k;
    const int kc = z - e * split_k;
    const int cnt = counts[e];
    const int m0 = blockIdx.x * 128;
    if (m0 >= cnt) return;
    const int n0 = blockIdx.y * 128;
    const int Kc = K / split_k;
    const int kb0 = kc * Kc;

    __shared__ __align__(16) bf16_t As[2][2][128][32];
    __shared__ __align__(16) bf16_t Bs[2][2][128][32];

    const int tid = threadIdx.x;
    // staging: row = tid>>1, 16 k-elems (2 chunks) at (tid&1)*16
    const int st_r = tid >> 1;
    const int st_c = tid & 1;
    const int sw_w = (st_r & 3) ^ ((st_r >> 2) & 3);
    const int wof0 = ((2 * st_c) ^ sw_w) * 8;
    const int wof1 = ((2 * st_c + 1) ^ sw_w) * 8;

    const int a_i = m0 + st_r;
    const int arow = rows[e * rows_es + (a_i < cnt ? a_i : cnt - 1)];
    const bf16_t* Aph = Ahi + (size_t)arow * a_rs + kb0 + st_c * 16;
    const bf16_t* Apl = Alo + (size_t)arow * a_rs + kb0 + st_c * 16;
    const bf16_t* Bph = Whi + (size_t)e * w_es + (size_t)(n0 + st_r) * K + kb0 + st_c * 16;
    const bf16_t* Bpl = Wlo + (size_t)e * w_es + (size_t)(n0 + st_r) * K + kb0 + st_c * 16;

    const int lane = tid & 63;
    const int w = tid >> 6;
    const int wm = (w >> 1) * 64, wn = (w & 1) * 64;
    const int fr = lane & 15;           // m (A/D-row side) or n (B/D-col side)
    const int cq = lane >> 4;           // k-quad
    const int sw_f = (fr & 3) ^ ((fr >> 2) & 3);
    const int koff = (cq ^ sw_f) * 8;   // swizzled k element offset

    f32x4 acc[4][4];
#pragma unroll
    for (int i = 0; i < 4; i++)
#pragma unroll
        for (int j = 0; j < 4; j++) acc[i][j] = (f32x4){0.f, 0.f, 0.f, 0.f};

    bf16x8 rah0 = *(const bf16x8*)(Aph);
    bf16x8 rah1 = *(const bf16x8*)(Aph + 8);
    bf16x8 ral0 = *(const bf16x8*)(Apl);
    bf16x8 ral1 = *(const bf16x8*)(Apl + 8);
    bf16x8 rbh0 = *(const bf16x8*)(Bph);
    bf16x8 rbh1 = *(const bf16x8*)(Bph + 8);
    bf16x8 rbl0 = *(const bf16x8*)(Bpl);
    bf16x8 rbl1 = *(const bf16x8*)(Bpl + 8);

    *(bf16x8*)&As[0][0][st_r][wof0] = rah0;
    *(bf16x8*)&As[0][0][st_r][wof1] = rah1;
    *(bf16x8*)&As[0][1][st_r][wof0] = ral0;
    *(bf16x8*)&As[0][1][st_r][wof1] = ral1;
    *(bf16x8*)&Bs[0][0][st_r][wof0] = rbh0;
    *(bf16x8*)&Bs[0][0][st_r][wof1] = rbh1;
    *(bf16x8*)&Bs[0][1][st_r][wof0] = rbl0;
    *(bf16x8*)&Bs[0][1][st_r][wof1] = rbl1;
    __syncthreads();

    const int nr = Kc / 32;
    int buf = 0;
    for (int r = 0; r < nr; r++) {
        if (r + 1 < nr) {
            const int ko = (r + 1) * 32;
            rah0 = *(const bf16x8*)(Aph + ko);
            rah1 = *(const bf16x8*)(Aph + ko + 8);
            ral0 = *(const bf16x8*)(Apl + ko);
            ral1 = *(const bf16x8*)(Apl + ko + 8);
            rbh0 = *(const bf16x8*)(Bph + ko);
            rbh1 = *(const bf16x8*)(Bph + ko + 8);
            rbl0 = *(const bf16x8*)(Bpl + ko);
            rbl1 = *(const bf16x8*)(Bpl + ko + 8);
        }
        bf16x8 ah[4], al2[4];
#pragma unroll
        for (int i = 0; i < 4; i++) {
            const int m_loc = wm + i * 16 + fr;
            ah[i]  = *(const bf16x8*)&As[buf][0][m_loc][koff];
            al2[i] = *(const bf16x8*)&As[buf][1][m_loc][koff];
        }
#pragma unroll
        for (int j = 0; j < 4; j++) {
            const int n_loc = wn + j * 16 + fr;
            const bf16x8 bh = *(const bf16x8*)&Bs[buf][0][n_loc][koff];
            const bf16x8 bl = *(const bf16x8*)&Bs[buf][1][n_loc][koff];
#pragma unroll
            for (int i = 0; i < 4; i++) {
                acc[i][j] = __builtin_amdgcn_mfma_f32_16x16x32_bf16(ah[i], bh, acc[i][j], 0, 0, 0);
                acc[i][j] = __builtin_amdgcn_mfma_f32_16x16x32_bf16(ah[i], bl, acc[i][j], 0, 0, 0);
                acc[i][j] = __builtin_amdgcn_mfma_f32_16x16x32_bf16(al2[i], bh, acc[i][j], 0, 0, 0);
            }
        }
        if (r + 1 < nr) {
            const int nb = buf ^ 1;
            *(bf16x8*)&As[nb][0][st_r][wof0] = rah0;
            *(bf16x8*)&As[nb][0][st_r][wof1] = rah1;
            *(bf16x8*)&As[nb][1][st_r][wof0] = ral0;
            *(bf16x8*)&As[nb][1][st_r][wof1] = ral1;
            *(bf16x8*)&Bs[nb][0][st_r][wof0] = rbh0;
            *(bf16x8*)&Bs[nb][0][st_r][wof1] = rbh1;
            *(bf16x8*)&Bs[nb][1][st_r][wof0] = rbl0;
            *(bf16x8*)&Bs[nb][1][st_r][wof1] = rbl1;
            __syncthreads();
            buf = nb;
        }
    }

    // epilogue: D mapping col=lane&15, row=(lane>>4)*4+reg  [m89/m91 verified]
    if (mode == 0) {
        float* Cb = C + (size_t)kc * c_es;
#pragma unroll
        for (int i = 0; i < 4; i++) {
#pragma unroll
            for (int rg = 0; rg < 4; rg++) {
                const int mi = m0 + wm + i * 16 + cq * 4 + rg;
                if (mi < cnt) {
                    const int row = rows[e * rows_es + mi];
#pragma unroll
                    for (int j = 0; j < 4; j++) {
                        const int col = n0 + wn + j * 16 + fr;
                        Cb[(size_t)row * c_rs + col] = acc[i][j][rg];
                    }
                }
            }
        }
    } else {
#pragma unroll
        for (int i = 0; i < 4; i++) {
#pragma unroll
            for (int rg = 0; rg < 4; rg++) {
                const int mi = m0 + wm + i * 16 + cq * 4 + rg;
                if (mi < cnt) {
                    const int row = rows[e * rows_es + mi];
#pragma unroll
                    for (int j = 0; j < 4; j++) {
                        const int col = n0 + wn + j * 16 + fr;
                        float x = acc[i][j][rg] + bias[e * bias_es + col];
                        x = fmaxf(x, 0.f);
                        const bf16_t hb = (bf16_t)x;
                        Chi[(size_t)row * cp_rs + col] = hb;
                        Clo[(size_t)row * cp_rs + col] = (bf16_t)(x - (float)hb);
                    }
                }
            }
        }
    }
}

// ---------------------------------------------------------------------------
// Router stage 2: logits = relu(R0+R1 + rb1) @ rW2 + rb2, argmax, terminate or
// bucket. One wave per sample.
// ---------------------------------------------------------------------------
__global__ __launch_bounds__(256) void router2_kernel(
    const float* __restrict__ R0, const float* __restrict__ R1,
    const float* __restrict__ rb1,
    const float* __restrict__ rW2, const float* __restrict__ rb2,
    const float* __restrict__ h,
    float* __restrict__ final_, const int* __restrict__ al,
    const int* __restrict__ n_act, int* __restrict__ counts,
    int* __restrict__ bucket, int* __restrict__ al_next,
    int* __restrict__ n_next, int* __restrict__ act_sel)
{
    const int n = *n_act;
    const int wid = threadIdx.x >> 6;
    const int lane = threadIdx.x & 63;
    const int i = blockIdx.x * 4 + wid;
    if (i >= n) return;
    const int s = al[i];
    const float* x0 = R0 + (size_t)s * D_;
    const float* x1 = R1 + (size_t)s * D_;
    float acc[E_ + 1];
#pragma unroll
    for (int c = 0; c <= E_; c++) acc[c] = 0.f;
    for (int j = 0; j < D_ / 64; j++) {
        const int d = j * 64 + lane;
        const float xv = fmaxf(x0[d] + x1[d] + rb1[d], 0.f);
        const float* wr = rW2 + (size_t)d * (E_ + 1);
#pragma unroll
        for (int c = 0; c <= E_; c++) acc[c] = fmaf(xv, wr[c], acc[c]);
    }
#pragma unroll
    for (int c = 0; c <= E_; c++) {
        float v = acc[c];
        for (int off = 32; off > 0; off >>= 1) v += __shfl_down(v, off, 64);
        acc[c] = v;
    }
    int best = 0;
    if (lane == 0) {
        float bv = acc[0] + rb2[0];
#pragma unroll
        for (int c = 1; c <= E_; c++) {
            const float v = acc[c] + rb2[c];
            if (v > bv) { bv = v; best = c; }   // strict '>' = first-max
        }
    }
    best = __shfl(best, 0, 64);
    if (best == E_) {
        const float* hs = h + (size_t)s * D_;
        float* fs = final_ + (size_t)s * D_;
        for (int d = lane * 4; d < D_; d += 64 * 4)
            *(float4*)(fs + d) = *(const float4*)(hs + d);
    } else if (lane == 0) {
        const int p = atomicAdd(&counts[best], 1);
        bucket[best * B_ + p] = s;
        const int q = atomicAdd(n_next, 1);
        al_next[q] = s;
        act_sel[s] = best;
    }
}

// ---------------------------------------------------------------------------
// LN + residual: h[s] += LN(Y0[s]+Y1[s] + b2_e)*g_e + beta_e; re-emit planes.
// ---------------------------------------------------------------------------
__global__ __launch_bounds__(256) void ln_update_kernel(
    float* __restrict__ h, bf16_t* __restrict__ hhi, bf16_t* __restrict__ hlo,
    const float* __restrict__ Y0, const float* __restrict__ Y1,
    const float* __restrict__ eb2, const float* __restrict__ eg,
    const float* __restrict__ ebeta, const int* __restrict__ al,
    const int* __restrict__ n_ptr, const int* __restrict__ act_sel)
{
    const int n = *n_ptr;
    const int i = blockIdx.x;
    if (i >= n) return;
    const int s = al[i];
    const int e = act_sel[s];
    const int t = threadIdx.x;
    const int lane = t & 63, wid = t >> 6;
    const int d0 = t * 4;

    const float4 y0v = *(const float4*)(Y0 + (size_t)s * D_ + d0);
    const float4 y1v = *(const float4*)(Y1 + (size_t)s * D_ + d0);
    const float4 bv = *(const float4*)(eb2 + (size_t)e * D_ + d0);
    float y0 = y0v.x + y1v.x + bv.x, y1 = y0v.y + y1v.y + bv.y;
    float y2 = y0v.z + y1v.z + bv.z, y3 = y0v.w + y1v.w + bv.w;

    __shared__ float wsum[4];
    __shared__ float stats[2];

    float ssum = y0 + y1 + y2 + y3;
    for (int off = 32; off > 0; off >>= 1) ssum += __shfl_down(ssum, off, 64);
    if (lane == 0) wsum[wid] = ssum;
    __syncthreads();
    if (t == 0) stats[0] = (wsum[0] + wsum[1] + wsum[2] + wsum[3]) * (1.f / D_);
    __syncthreads();
    const float m = stats[0];
    const float e0 = y0 - m, e1 = y1 - m, e2 = y2 - m, e3 = y3 - m;
    float sq = e0 * e0 + e1 * e1 + e2 * e2 + e3 * e3;
    for (int off = 32; off > 0; off >>= 1) sq += __shfl_down(sq, off, 64);
    if (lane == 0) wsum[wid] = sq;
    __syncthreads();
    if (t == 0) {
        const float var = (wsum[0] + wsum[1] + wsum[2] + wsum[3]) * (1.f / D_);
        stats[1] = 1.0f / sqrtf(var + 1e-5f);
    }
    __syncthreads();
    const float rs = stats[1];

    const float4 gv = *(const float4*)(eg + (size_t)e * D_ + d0);
    const float4 btv = *(const float4*)(ebeta + (size_t)e * D_ + d0);
    float* hp = h + (size_t)s * D_ + d0;
    float4 hv = *(const float4*)hp;
    float r[4];
    r[0] = hv.x + e0 * rs * gv.x + btv.x;
    r[1] = hv.y + e1 * rs * gv.y + btv.y;
    r[2] = hv.z + e2 * rs * gv.z + btv.z;
    r[3] = hv.w + e3 * rs * gv.w + btv.w;
    *(float4*)hp = *(float4*)r;
    bf16x4 hq, lq;
#pragma unroll
    for (int q = 0; q < 4; q++) {
        const bf16_t hb = (bf16_t)r[q];
        hq[q] = hb;
        lq[q] = (bf16_t)(r[q] - (float)hb);
    }
    *(bf16x4*)(hhi + (size_t)s * D_ + d0) = hq;
    *(bf16x4*)(hlo + (size_t)s * D_ + d0) = lq;
}

__global__ void reset_kernel(int* __restrict__ counts, int* __restrict__ n_next)
{
    const int t = threadIdx.x;
    if (t < E_) counts[t] = 0;
    if (t == E_) *n_next = 0;
}

__global__ __launch_bounds__(256) void finalize_kernel(
    const int* __restrict__ al, const int* __restrict__ n_ptr,
    const float* __restrict__ h, float* __restrict__ final_)
{
    const int n = *n_ptr;
    const int i = blockIdx.x;
    if (i >= n) return;
    const int s = al[i];
    const int d0 = threadIdx.x * 4;
    *(float4*)(final_ + (size_t)s * D_ + d0) =
        *(const float4*)(h + (size_t)s * D_ + d0);
}

// out[s, 0..9] = final[s] @ oW + ob
__global__ __launch_bounds__(256) void out_head_kernel(
    const float* __restrict__ final_, const float* __restrict__ oW,
    const float* __restrict__ ob, float* __restrict__ out)
{
    const int s = blockIdx.x;
    const int t = threadIdx.x;
    const int lane = t & 63, wid = t >> 6;
    float p[NC];
#pragma unroll
    for (int c = 0; c < NC; c++) p[c] = 0.f;
    for (int d = t; d < D_; d += 256) {
        const float x = final_[(size_t)s * D_ + d];
        const float* wr = oW + (size_t)d * NC;
#pragma unroll
        for (int c = 0; c < NC; c++) p[c] = fmaf(x, wr[c], p[c]);
    }
#pragma unroll
    for (int c = 0; c < NC; c++) {
        float v = p[c];
        for (int off = 32; off > 0; off >>= 1) v += __shfl_down(v, off, 64);
        p[c] = v;
    }
    __shared__ float red[4][NC];
    if (lane == 0) {
#pragma unroll
        for (int c = 0; c < NC; c++) red[wid][c] = p[c];
    }
    __syncthreads();
    if (t < NC)
        out[(size_t)s * NC + t] =
            red[0][t] + red[1][t] + red[2][t] + red[3][t] + ob[t];
}

// ---------------------------------------------------------------------------
extern "C" void kernel_launch(void* const* d_in, const int* in_sizes, int n_in,
                              void* d_out, int out_size, void* d_ws, size_t ws_size,
                              hipStream_t stream)
{
    const int*   ids   = (const int*)d_in[0];
    const float* emb   = (const float*)d_in[1];
    const float* rW1   = (const float*)d_in[2];
    const float* rb1   = (const float*)d_in[3];
    const float* rW2   = (const float*)d_in[4];
    const float* rb2   = (const float*)d_in[5];
    const float* eW1   = (const float*)d_in[6];
    const float* eb1   = (const float*)d_in[7];
    const float* eW2   = (const float*)d_in[8];
    const float* eb2   = (const float*)d_in[9];
    const float* eg    = (const float*)d_in[10];
    const float* ebeta = (const float*)d_in[11];
    const float* oW    = (const float*)d_in[12];
    const float* ob    = (const float*)d_in[13];
    float* out = (float*)d_out;

    // ---- workspace layout ----
    float* h   = (float*)d_ws;                   // B*D
    float* fin = h + (size_t)B_ * D_;            // B*D
    float* Y0  = fin + (size_t)B_ * D_;          // B*D (also router partial R0)
    float* Y1  = Y0 + (size_t)B_ * D_;           // B*D (also router partial R1)
    bf16_t* hhi   = (bf16_t*)(Y1 + (size_t)B_ * D_);   // B*D
    bf16_t* hlo   = hhi + (size_t)B_ * D_;             // B*D
    bf16_t* Zhi   = hlo + (size_t)B_ * D_;             // B*H
    bf16_t* Zlo   = Zhi + (size_t)B_ * H_;             // B*H
    bf16_t* rW1h  = Zlo + (size_t)B_ * H_;             // D*D  ([N][K])
    bf16_t* rW1l  = rW1h + (size_t)D_ * D_;            // D*D
    bf16_t* eW1h  = rW1l + (size_t)D_ * D_;            // E*H*D ([e][N=H][K=D])
    bf16_t* eW1l  = eW1h + (size_t)E_ * H_ * D_;
    bf16_t* eW2h  = eW1l + (size_t)E_ * H_ * D_;       // E*D*H ([e][N=D][K=H])
    bf16_t* eW2l  = eW2h + (size_t)E_ * D_ * H_;
    int* alA     = (int*)(eW2l + (size_t)E_ * D_ * H_);  // B
    int* alB     = alA + B_;                             // B
    int* bucket  = alB + B_;                             // E*B
    int* counts  = bucket + E_ * B_;                     // E
    int* nA      = counts + E_;                          // 1
    int* nB      = nA + 1;                               // 1
    int* act_sel = nB + 1;                               // B

    // ---- one-time (per call) weight plane conversion ----
    conv_w_kernel<<<dim3(D_ / 32, D_ / 32, 1), 256, 0, stream>>>(rW1, rW1h, rW1l, D_, D_);
    conv_w_kernel<<<dim3(D_ / 32, H_ / 32, E_), 256, 0, stream>>>(eW1, eW1h, eW1l, D_, H_);
    conv_w_kernel<<<dim3(H_ / 32, D_ / 32, E_), 256, 0, stream>>>(eW2, eW2h, eW2l, H_, D_);

    pool_kernel<<<B_, 256, 0, stream>>>(ids, emb, h, hhi, hlo, alA, nA);

    int* al_in = alA; int* n_in_p = nA;
    int* al_out = alB; int* n_out_p = nB;

    for (int step = 0; step < STEPS_; step++) {
        reset_kernel<<<1, 64, 0, stream>>>(counts, n_out_p);

        // router hidden partials: R0/R1 = (h @ rW1) split-K 2 (rb1+relu in router2)
        gemm_mfma<<<dim3(16, D_ / 128, 2), 256, 0, stream>>>(
            hhi, hlo, D_, rW1h, rW1l, 0, D_, D_,
            nullptr, 0,
            Y0, (long long)B_ * D_, D_,
            nullptr, nullptr, 0,
            al_in, 0, n_in_p, 2, 0);

        router2_kernel<<<B_ / 4, 256, 0, stream>>>(
            Y0, Y1, rb1, rW2, rb2, h, fin, al_in, n_in_p,
            counts, bucket, al_out, n_out_p, act_sel);

        // expert L1: Z = relu(h @ eW1_e + eb1_e) -> bf16 planes (fused epilogue)
        gemm_mfma<<<dim3(16, H_ / 128, E_), 256, 0, stream>>>(
            hhi, hlo, D_, eW1h, eW1l, (long long)H_ * D_, H_, D_,
            eb1, H_,
            nullptr, 0, 0,
            Zhi, Zlo, H_,
            bucket, B_, counts, 1, 2);

        // expert L2 partials: Y0/Y1 = (Z @ eW2_e) split-K 2 (eb2 in LN)
        gemm_mfma<<<dim3(16, D_ / 128, E_ * 2), 256, 0, stream>>>(
            Zhi, Zlo, H_, eW2h, eW2l, (long long)D_ * H_, D_, H_,
            nullptr, 0,
            Y0, (long long)B_ * D_, D_,
            nullptr, nullptr, 0,
            bucket, B_, counts, 2, 0);

        ln_update_kernel<<<B_, 256, 0, stream>>>(
            h, hhi, hlo, Y0, Y1, eb2, eg, ebeta, al_out, n_out_p, act_sel);

        int* ta = al_in; al_in = al_out; al_out = ta;
        int* tn = n_in_p; n_in_p = n_out_p; n_out_p = tn;
    }

    finalize_kernel<<<B_, 256, 0, stream>>>(al_in, n_in_p, h, fin);
    out_head_kernel<<<B_, 256, 0, stream>>>(fin, oW, ob, out);
}

// Round 5
// 1284.727 us; speedup vs baseline: 6.3561x; 1.9971x over previous
//
#include <hip/hip_runtime.h>

#define B_ 2048
#define S_ 128
#define D_ 1024
#define H_ 2048
#define E_ 8
#define NC 10
#define STEPS_ 5

typedef __bf16 bf16_t;
typedef __bf16 bf16x8 __attribute__((ext_vector_type(8)));
typedef __bf16 bf16x4 __attribute__((ext_vector_type(4)));
typedef float f32x4 __attribute__((ext_vector_type(4)));

// ---------------------------------------------------------------------------
// Pool: h[b] = masked mean over S of emb[ids[b,s]]; emits fp32 h + bf16 hi/lo
// planes; inits active list.
// ---------------------------------------------------------------------------
__global__ __launch_bounds__(256) void pool_kernel(
    const int* __restrict__ ids, const float* __restrict__ emb,
    float* __restrict__ h, bf16_t* __restrict__ hhi, bf16_t* __restrict__ hlo,
    int* __restrict__ al, int* __restrict__ n_act)
{
    const int b = blockIdx.x;
    const int t = threadIdx.x;
    __shared__ int sid[S_];
    __shared__ float scnt;
    if (t < S_) sid[t] = ids[b * S_ + t];
    __syncthreads();
    if (t == 0) {
        int c = 0;
        for (int j = 0; j < S_; j++) c += (sid[j] != 0) ? 1 : 0;
        scnt = (c > 0) ? (float)c : 1.0f;
    }
    const int d0 = t * 4;
    float ax = 0.f, ay = 0.f, az = 0.f, aw = 0.f;
    for (int j = 0; j < S_; j++) {
        const int id = sid[j];
        if (id != 0) {
            const float4 v = *(const float4*)(emb + (size_t)id * D_ + d0);
            ax += v.x; ay += v.y; az += v.z; aw += v.w;
        }
    }
    __syncthreads();
    const float c = scnt;
    float r[4] = {ax / c, ay / c, az / c, aw / c};
    *(float4*)(h + (size_t)b * D_ + d0) = *(float4*)r;
    bf16x4 hv, lv;
#pragma unroll
    for (int q = 0; q < 4; q++) {
        bf16_t hb = (bf16_t)r[q];
        hv[q] = hb;
        lv[q] = (bf16_t)(r[q] - (float)hb);
    }
    *(bf16x4*)(hhi + (size_t)b * D_ + d0) = hv;
    *(bf16x4*)(hlo + (size_t)b * D_ + d0) = lv;
    if (t == 0) {
        al[b] = b;
        if (b == 0) *n_act = B_;
    }
}

// ---------------------------------------------------------------------------
// Weight convert+transpose: W[e][K][N] fp32 -> hi/lo bf16 planes [e][N][K].
// 32x32 tiles through LDS; grid (K/32, N/32, E).
// ---------------------------------------------------------------------------
__global__ __launch_bounds__(256) void conv_w_kernel(
    const float* __restrict__ W, bf16_t* __restrict__ hi, bf16_t* __restrict__ lo,
    int K, int N)
{
    const int e = blockIdx.z;
    const int k0 = blockIdx.x * 32, n0 = blockIdx.y * 32;
    const float* We = W + (size_t)e * K * N;
    bf16_t* he = hi + (size_t)e * N * K;
    bf16_t* le = lo + (size_t)e * N * K;
    __shared__ float t[32][33];
    const int tid = threadIdx.x;
    const int r = tid >> 3, c4 = (tid & 7) * 4;
    *(float4*)&t[r][c4] = *(const float4*)(We + (size_t)(k0 + r) * N + n0 + c4);
    __syncthreads();
    const int n = r, k4 = c4;
    bf16x4 hv, lv;
#pragma unroll
    for (int q = 0; q < 4; q++) {
        const float x = t[k4 + q][n];
        bf16_t hb = (bf16_t)x;
        hv[q] = hb;
        lv[q] = (bf16_t)(x - (float)hb);
    }
    *(bf16x4*)(he + (size_t)(n0 + n) * K + k0 + k4) = hv;
    *(bf16x4*)(le + (size_t)(n0 + n) * K + k0 + k4) = lv;
}

// ---------------------------------------------------------------------------
// Split-bf16 MFMA gathered GEMM.  C[rows[i]] = sum_k A[rows[i]][k] * W_e[k][n]
// A planes: [*][K] bf16 (k-contig). W planes: [e][N][K] bf16 (k-contig).
// Block 128x128, 4 waves x (64x64), BK=32 (one mfma-K per round).
// XOR-swizzled LDS chunks (16B), single barrier/round, depth-1 prefetch.
// mode 0: store fp32 partial to C + kc*c_es  (split-K, no bias)
// mode 2: x = relu(acc + bias[e][col]); split-store to Chi/Clo bf16 planes
// Grid: (N/128, ceil(maxM/128), E*split_k) -- N-tiles on blockIdx.x so real
// blocks cover all values of (linear_id % 8) => uniform XCD spread.  [R5 fix]
// ---------------------------------------------------------------------------
__global__ __launch_bounds__(256, 2) void gemm_mfma(
    const bf16_t* __restrict__ Ahi, const bf16_t* __restrict__ Alo, int a_rs,
    const bf16_t* __restrict__ Whi, const bf16_t* __restrict__ Wlo, long long w_es,
    int N, int K,
    const float* __restrict__ bias, int bias_es,
    float* __restrict__ C, long long c_es, int c_rs,
    bf16_t* __restrict__ Chi, bf16_t* __restrict__ Clo, int cp_rs,
    const int* __restrict__ rows, int rows_es,
    const int* __restrict__ counts,
    int split_k, int mode)
{
    const int z = blockIdx.z;
    const int e = z / split_k;
    const int kc = z - e * split_k;
    const int cnt = counts[e];
    const int m0 = blockIdx.y * 128;      // [R5] m on y
    if (m0 >= cnt) return;
    const int n0 = blockIdx.x * 128;      // [R5] n on x (all real)
    const int Kc = K / split_k;
    const int kb0 = kc * Kc;

    __shared__ __align__(16) bf16_t As[2][2][128][32];
    __shared__ __align__(16) bf16_t Bs[2][2][128][32];

    const int tid = threadIdx.x;
    // staging: row = tid>>1, 16 k-elems (2 chunks) at (tid&1)*16
    const int st_r = tid >> 1;
    const int st_c = tid & 1;
    const int sw_w = (st_r & 3) ^ ((st_r >> 2) & 3);
    const int wof0 = ((2 * st_c) ^ sw_w) * 8;
    const int wof1 = ((2 * st_c + 1) ^ sw_w) * 8;

    const int a_i = m0 + st_r;
    const int arow = rows[e * rows_es + (a_i < cnt ? a_i : cnt - 1)];
    const bf16_t* Aph = Ahi + (size_t)arow * a_rs + kb0 + st_c * 16;
    const bf16_t* Apl = Alo + (size_t)arow * a_rs + kb0 + st_c * 16;
    const bf16_t* Bph = Whi + (size_t)e * w_es + (size_t)(n0 + st_r) * K + kb0 + st_c * 16;
    const bf16_t* Bpl = Wlo + (size_t)e * w_es + (size_t)(n0 + st_r) * K + kb0 + st_c * 16;

    const int lane = tid & 63;
    const int w = tid >> 6;
    const int wm = (w >> 1) * 64, wn = (w & 1) * 64;
    const int fr = lane & 15;           // m (A/D-row side) or n (B/D-col side)
    const int cq = lane >> 4;           // k-quad
    const int sw_f = (fr & 3) ^ ((fr >> 2) & 3);
    const int koff = (cq ^ sw_f) * 8;   // swizzled k element offset

    f32x4 acc[4][4];
#pragma unroll
    for (int i = 0; i < 4; i++)
#pragma unroll
        for (int j = 0; j < 4; j++) acc[i][j] = (f32x4){0.f, 0.f, 0.f, 0.f};

    bf16x8 rah0 = *(const bf16x8*)(Aph);
    bf16x8 rah1 = *(const bf16x8*)(Aph + 8);
    bf16x8 ral0 = *(const bf16x8*)(Apl);
    bf16x8 ral1 = *(const bf16x8*)(Apl + 8);
    bf16x8 rbh0 = *(const bf16x8*)(Bph);
    bf16x8 rbh1 = *(const bf16x8*)(Bph + 8);
    bf16x8 rbl0 = *(const bf16x8*)(Bpl);
    bf16x8 rbl1 = *(const bf16x8*)(Bpl + 8);

    *(bf16x8*)&As[0][0][st_r][wof0] = rah0;
    *(bf16x8*)&As[0][0][st_r][wof1] = rah1;
    *(bf16x8*)&As[0][1][st_r][wof0] = ral0;
    *(bf16x8*)&As[0][1][st_r][wof1] = ral1;
    *(bf16x8*)&Bs[0][0][st_r][wof0] = rbh0;
    *(bf16x8*)&Bs[0][0][st_r][wof1] = rbh1;
    *(bf16x8*)&Bs[0][1][st_r][wof0] = rbl0;
    *(bf16x8*)&Bs[0][1][st_r][wof1] = rbl1;
    __syncthreads();

    const int nr = Kc / 32;
    int buf = 0;
    for (int r = 0; r < nr; r++) {
        if (r + 1 < nr) {
            const int ko = (r + 1) * 32;
            rah0 = *(const bf16x8*)(Aph + ko);
            rah1 = *(const bf16x8*)(Aph + ko + 8);
            ral0 = *(const bf16x8*)(Apl + ko);
            ral1 = *(const bf16x8*)(Apl + ko + 8);
            rbh0 = *(const bf16x8*)(Bph + ko);
            rbh1 = *(const bf16x8*)(Bph + ko + 8);
            rbl0 = *(const bf16x8*)(Bpl + ko);
            rbl1 = *(const bf16x8*)(Bpl + ko + 8);
        }
        bf16x8 ah[4], al2[4];
#pragma unroll
        for (int i = 0; i < 4; i++) {
            const int m_loc = wm + i * 16 + fr;
            ah[i]  = *(const bf16x8*)&As[buf][0][m_loc][koff];
            al2[i] = *(const bf16x8*)&As[buf][1][m_loc][koff];
        }
#pragma unroll
        for (int j = 0; j < 4; j++) {
            const int n_loc = wn + j * 16 + fr;
            const bf16x8 bh = *(const bf16x8*)&Bs[buf][0][n_loc][koff];
            const bf16x8 bl = *(const bf16x8*)&Bs[buf][1][n_loc][koff];
#pragma unroll
            for (int i = 0; i < 4; i++) {
                acc[i][j] = __builtin_amdgcn_mfma_f32_16x16x32_bf16(ah[i], bh, acc[i][j], 0, 0, 0);
                acc[i][j] = __builtin_amdgcn_mfma_f32_16x16x32_bf16(ah[i], bl, acc[i][j], 0, 0, 0);
                acc[i][j] = __builtin_amdgcn_mfma_f32_16x16x32_bf16(al2[i], bh, acc[i][j], 0, 0, 0);
            }
        }
        if (r + 1 < nr) {
            const int nb = buf ^ 1;
            *(bf16x8*)&As[nb][0][st_r][wof0] = rah0;
            *(bf16x8*)&As[nb][0][st_r][wof1] = rah1;
            *(bf16x8*)&As[nb][1][st_r][wof0] = ral0;
            *(bf16x8*)&As[nb][1][st_r][wof1] = ral1;
            *(bf16x8*)&Bs[nb][0][st_r][wof0] = rbh0;
            *(bf16x8*)&Bs[nb][0][st_r][wof1] = rbh1;
            *(bf16x8*)&Bs[nb][1][st_r][wof0] = rbl0;
            *(bf16x8*)&Bs[nb][1][st_r][wof1] = rbl1;
            __syncthreads();
            buf = nb;
        }
    }

    // epilogue: D mapping col=lane&15, row=(lane>>4)*4+reg  [m89/m91 verified]
    if (mode == 0) {
        float* Cb = C + (size_t)kc * c_es;
#pragma unroll
        for (int i = 0; i < 4; i++) {
#pragma unroll
            for (int rg = 0; rg < 4; rg++) {
                const int mi = m0 + wm + i * 16 + cq * 4 + rg;
                if (mi < cnt) {
                    const int row = rows[e * rows_es + mi];
#pragma unroll
                    for (int j = 0; j < 4; j++) {
                        const int col = n0 + wn + j * 16 + fr;
                        Cb[(size_t)row * c_rs + col] = acc[i][j][rg];
                    }
                }
            }
        }
    } else {
#pragma unroll
        for (int i = 0; i < 4; i++) {
#pragma unroll
            for (int rg = 0; rg < 4; rg++) {
                const int mi = m0 + wm + i * 16 + cq * 4 + rg;
                if (mi < cnt) {
                    const int row = rows[e * rows_es + mi];
#pragma unroll
                    for (int j = 0; j < 4; j++) {
                        const int col = n0 + wn + j * 16 + fr;
                        float x = acc[i][j][rg] + bias[e * bias_es + col];
                        x = fmaxf(x, 0.f);
                        const bf16_t hb = (bf16_t)x;
                        Chi[(size_t)row * cp_rs + col] = hb;
                        Clo[(size_t)row * cp_rs + col] = (bf16_t)(x - (float)hb);
                    }
                }
            }
        }
    }
}

// ---------------------------------------------------------------------------
// Router stage 2: logits = relu(R0+R1 + rb1) @ rW2 + rb2, argmax, terminate or
// bucket. One wave per sample.
// ---------------------------------------------------------------------------
__global__ __launch_bounds__(256) void router2_kernel(
    const float* __restrict__ R0, const float* __restrict__ R1,
    const float* __restrict__ rb1,
    const float* __restrict__ rW2, const float* __restrict__ rb2,
    const float* __restrict__ h,
    float* __restrict__ final_, const int* __restrict__ al,
    const int* __restrict__ n_act, int* __restrict__ counts,
    int* __restrict__ bucket, int* __restrict__ al_next,
    int* __restrict__ n_next, int* __restrict__ act_sel)
{
    const int n = *n_act;
    const int wid = threadIdx.x >> 6;
    const int lane = threadIdx.x & 63;
    const int i = blockIdx.x * 4 + wid;
    if (i >= n) return;
    const int s = al[i];
    const float* x0 = R0 + (size_t)s * D_;
    const float* x1 = R1 + (size_t)s * D_;
    float acc[E_ + 1];
#pragma unroll
    for (int c = 0; c <= E_; c++) acc[c] = 0.f;
    for (int j = 0; j < D_ / 64; j++) {
        const int d = j * 64 + lane;
        const float xv = fmaxf(x0[d] + x1[d] + rb1[d], 0.f);
        const float* wr = rW2 + (size_t)d * (E_ + 1);
#pragma unroll
        for (int c = 0; c <= E_; c++) acc[c] = fmaf(xv, wr[c], acc[c]);
    }
#pragma unroll
    for (int c = 0; c <= E_; c++) {
        float v = acc[c];
        for (int off = 32; off > 0; off >>= 1) v += __shfl_down(v, off, 64);
        acc[c] = v;
    }
    int best = 0;
    if (lane == 0) {
        float bv = acc[0] + rb2[0];
#pragma unroll
        for (int c = 1; c <= E_; c++) {
            const float v = acc[c] + rb2[c];
            if (v > bv) { bv = v; best = c; }   // strict '>' = first-max
        }
    }
    best = __shfl(best, 0, 64);
    if (best == E_) {
        const float* hs = h + (size_t)s * D_;
        float* fs = final_ + (size_t)s * D_;
        for (int d = lane * 4; d < D_; d += 64 * 4)
            *(float4*)(fs + d) = *(const float4*)(hs + d);
    } else if (lane == 0) {
        const int p = atomicAdd(&counts[best], 1);
        bucket[best * B_ + p] = s;
        const int q = atomicAdd(n_next, 1);
        al_next[q] = s;
        act_sel[s] = best;
    }
}

// ---------------------------------------------------------------------------
// LN + residual: h[s] += LN(Y0[s]+Y1[s] + b2_e)*g_e + beta_e; re-emit planes.
// ---------------------------------------------------------------------------
__global__ __launch_bounds__(256) void ln_update_kernel(
    float* __restrict__ h, bf16_t* __restrict__ hhi, bf16_t* __restrict__ hlo,
    const float* __restrict__ Y0, const float* __restrict__ Y1,
    const float* __restrict__ eb2, const float* __restrict__ eg,
    const float* __restrict__ ebeta, const int* __restrict__ al,
    const int* __restrict__ n_ptr, const int* __restrict__ act_sel)
{
    const int n = *n_ptr;
    const int i = blockIdx.x;
    if (i >= n) return;
    const int s = al[i];
    const int e = act_sel[s];
    const int t = threadIdx.x;
    const int lane = t & 63, wid = t >> 6;
    const int d0 = t * 4;

    const float4 y0v = *(const float4*)(Y0 + (size_t)s * D_ + d0);
    const float4 y1v = *(const float4*)(Y1 + (size_t)s * D_ + d0);
    const float4 bv = *(const float4*)(eb2 + (size_t)e * D_ + d0);
    float y0 = y0v.x + y1v.x + bv.x, y1 = y0v.y + y1v.y + bv.y;
    float y2 = y0v.z + y1v.z + bv.z, y3 = y0v.w + y1v.w + bv.w;

    __shared__ float wsum[4];
    __shared__ float stats[2];

    float ssum = y0 + y1 + y2 + y3;
    for (int off = 32; off > 0; off >>= 1) ssum += __shfl_down(ssum, off, 64);
    if (lane == 0) wsum[wid] = ssum;
    __syncthreads();
    if (t == 0) stats[0] = (wsum[0] + wsum[1] + wsum[2] + wsum[3]) * (1.f / D_);
    __syncthreads();
    const float m = stats[0];
    const float e0 = y0 - m, e1 = y1 - m, e2 = y2 - m, e3 = y3 - m;
    float sq = e0 * e0 + e1 * e1 + e2 * e2 + e3 * e3;
    for (int off = 32; off > 0; off >>= 1) sq += __shfl_down(sq, off, 64);
    if (lane == 0) wsum[wid] = sq;
    __syncthreads();
    if (t == 0) {
        const float var = (wsum[0] + wsum[1] + wsum[2] + wsum[3]) * (1.f / D_);
        stats[1] = 1.0f / sqrtf(var + 1e-5f);
    }
    __syncthreads();
    const float rs = stats[1];

    const float4 gv = *(const float4*)(eg + (size_t)e * D_ + d0);
    const float4 btv = *(const float4*)(ebeta + (size_t)e * D_ + d0);
    float* hp = h + (size_t)s * D_ + d0;
    float4 hv = *(const float4*)hp;
    float r[4];
    r[0] = hv.x + e0 * rs * gv.x + btv.x;
    r[1] = hv.y + e1 * rs * gv.y + btv.y;
    r[2] = hv.z + e2 * rs * gv.z + btv.z;
    r[3] = hv.w + e3 * rs * gv.w + btv.w;
    *(float4*)hp = *(float4*)r;
    bf16x4 hq, lq;
#pragma unroll
    for (int q = 0; q < 4; q++) {
        const bf16_t hb = (bf16_t)r[q];
        hq[q] = hb;
        lq[q] = (bf16_t)(r[q] - (float)hb);
    }
    *(bf16x4*)(hhi + (size_t)s * D_ + d0) = hq;
    *(bf16x4*)(hlo + (size_t)s * D_ + d0) = lq;
}

__global__ void reset_kernel(int* __restrict__ counts, int* __restrict__ n_next)
{
    const int t = threadIdx.x;
    if (t < E_) counts[t] = 0;
    if (t == E_) *n_next = 0;
}

__global__ __launch_bounds__(256) void finalize_kernel(
    const int* __restrict__ al, const int* __restrict__ n_ptr,
    const float* __restrict__ h, float* __restrict__ final_)
{
    const int n = *n_ptr;
    const int i = blockIdx.x;
    if (i >= n) return;
    const int s = al[i];
    const int d0 = threadIdx.x * 4;
    *(float4*)(final_ + (size_t)s * D_ + d0) =
        *(const float4*)(h + (size_t)s * D_ + d0);
}

// out[s, 0..9] = final[s] @ oW + ob
__global__ __launch_bounds__(256) void out_head_kernel(
    const float* __restrict__ final_, const float* __restrict__ oW,
    const float* __restrict__ ob, float* __restrict__ out)
{
    const int s = blockIdx.x;
    const int t = threadIdx.x;
    const int lane = t & 63, wid = t >> 6;
    float p[NC];
#pragma unroll
    for (int c = 0; c < NC; c++) p[c] = 0.f;
    for (int d = t; d < D_; d += 256) {
        const float x = final_[(size_t)s * D_ + d];
        const float* wr = oW + (size_t)d * NC;
#pragma unroll
        for (int c = 0; c < NC; c++) p[c] = fmaf(x, wr[c], p[c]);
    }
#pragma unroll
    for (int c = 0; c < NC; c++) {
        float v = p[c];
        for (int off = 32; off > 0; off >>= 1) v += __shfl_down(v, off, 64);
        p[c] = v;
    }
    __shared__ float red[4][NC];
    if (lane == 0) {
#pragma unroll
        for (int c = 0; c < NC; c++) red[wid][c] = p[c];
    }
    __syncthreads();
    if (t < NC)
        out[(size_t)s * NC + t] =
            red[0][t] + red[1][t] + red[2][t] + red[3][t] + ob[t];
}

// ---------------------------------------------------------------------------
extern "C" void kernel_launch(void* const* d_in, const int* in_sizes, int n_in,
                              void* d_out, int out_size, void* d_ws, size_t ws_size,
                              hipStream_t stream)
{
    const int*   ids   = (const int*)d_in[0];
    const float* emb   = (const float*)d_in[1];
    const float* rW1   = (const float*)d_in[2];
    const float* rb1   = (const float*)d_in[3];
    const float* rW2   = (const float*)d_in[4];
    const float* rb2   = (const float*)d_in[5];
    const float* eW1   = (const float*)d_in[6];
    const float* eb1   = (const float*)d_in[7];
    const float* eW2   = (const float*)d_in[8];
    const float* eb2   = (const float*)d_in[9];
    const float* eg    = (const float*)d_in[10];
    const float* ebeta = (const float*)d_in[11];
    const float* oW    = (const float*)d_in[12];
    const float* ob    = (const float*)d_in[13];
    float* out = (float*)d_out;

    // ---- workspace layout ----
    float* h   = (float*)d_ws;                   // B*D
    float* fin = h + (size_t)B_ * D_;            // B*D
    float* Y0  = fin + (size_t)B_ * D_;          // B*D (also router partial R0)
    float* Y1  = Y0 + (size_t)B_ * D_;           // B*D (also router partial R1)
    bf16_t* hhi   = (bf16_t*)(Y1 + (size_t)B_ * D_);   // B*D
    bf16_t* hlo   = hhi + (size_t)B_ * D_;             // B*D
    bf16_t* Zhi   = hlo + (size_t)B_ * D_;             // B*H
    bf16_t* Zlo   = Zhi + (size_t)B_ * H_;             // B*H
    bf16_t* rW1h  = Zlo + (size_t)B_ * H_;             // D*D  ([N][K])
    bf16_t* rW1l  = rW1h + (size_t)D_ * D_;            // D*D
    bf16_t* eW1h  = rW1l + (size_t)D_ * D_;            // E*H*D ([e][N=H][K=D])
    bf16_t* eW1l  = eW1h + (size_t)E_ * H_ * D_;
    bf16_t* eW2h  = eW1l + (size_t)E_ * H_ * D_;       // E*D*H ([e][N=D][K=H])
    bf16_t* eW2l  = eW2h + (size_t)E_ * D_ * H_;
    int* alA     = (int*)(eW2l + (size_t)E_ * D_ * H_);  // B
    int* alB     = alA + B_;                             // B
    int* bucket  = alB + B_;                             // E*B
    int* counts  = bucket + E_ * B_;                     // E
    int* nA      = counts + E_;                          // 1
    int* nB      = nA + 1;                               // 1
    int* act_sel = nB + 1;                               // B

    // ---- one-time (per call) weight plane conversion ----
    conv_w_kernel<<<dim3(D_ / 32, D_ / 32, 1), 256, 0, stream>>>(rW1, rW1h, rW1l, D_, D_);
    conv_w_kernel<<<dim3(D_ / 32, H_ / 32, E_), 256, 0, stream>>>(eW1, eW1h, eW1l, D_, H_);
    conv_w_kernel<<<dim3(H_ / 32, D_ / 32, E_), 256, 0, stream>>>(eW2, eW2h, eW2l, H_, D_);

    pool_kernel<<<B_, 256, 0, stream>>>(ids, emb, h, hhi, hlo, alA, nA);

    int* al_in = alA; int* n_in_p = nA;
    int* al_out = alB; int* n_out_p = nB;

    for (int step = 0; step < STEPS_; step++) {
        reset_kernel<<<1, 64, 0, stream>>>(counts, n_out_p);

        // router hidden partials: R0/R1 = (h @ rW1) split-K 2 (rb1+relu in router2)
        // [R5] grid: x = N-tiles (all real), y = M-tiles
        gemm_mfma<<<dim3(D_ / 128, 16, 2), 256, 0, stream>>>(
            hhi, hlo, D_, rW1h, rW1l, 0, D_, D_,
            nullptr, 0,
            Y0, (long long)B_ * D_, D_,
            nullptr, nullptr, 0,
            al_in, 0, n_in_p, 2, 0);

        router2_kernel<<<B_ / 4, 256, 0, stream>>>(
            Y0, Y1, rb1, rW2, rb2, h, fin, al_in, n_in_p,
            counts, bucket, al_out, n_out_p, act_sel);

        // expert L1: Z = relu(h @ eW1_e + eb1_e) -> bf16 planes (fused epilogue)
        gemm_mfma<<<dim3(H_ / 128, 16, E_), 256, 0, stream>>>(
            hhi, hlo, D_, eW1h, eW1l, (long long)H_ * D_, H_, D_,
            eb1, H_,
            nullptr, 0, 0,
            Zhi, Zlo, H_,
            bucket, B_, counts, 1, 2);

        // expert L2 partials: Y0/Y1 = (Z @ eW2_e) split-K 2 (eb2 in LN)
        gemm_mfma<<<dim3(D_ / 128, 16, E_ * 2), 256, 0, stream>>>(
            Zhi, Zlo, H_, eW2h, eW2l, (long long)D_ * H_, D_, H_,
            nullptr, 0,
            Y0, (long long)B_ * D_, D_,
            nullptr, nullptr, 0,
            bucket, B_, counts, 2, 0);

        ln_update_kernel<<<B_, 256, 0, stream>>>(
            h, hhi, hlo, Y0, Y1, eb2, eg, ebeta, al_out, n_out_p, act_sel);

        int* ta = al_in; al_in = al_out; al_out = ta;
        int* tn = n_in_p; n_in_p = n_out_p; n_out_p = tn;
    }

    finalize_kernel<<<B_, 256, 0, stream>>>(al_in, n_in_p, h, fin);
    out_head_kernel<<<B_, 256, 0, stream>>>(fin, oW, ob, out);
}